// Round 1
// baseline (18223.320 us; speedup 1.0000x reference)
//
#include <hip/hip_runtime.h>
#include <math.h>

// Fused 2-layer SimpleRNN, fp32 baseline.
// Per step t (80 steps):
//   h1' = tanh( emb[tokens[:,t]] @ W1 + h1 @ U1 + b1 )   (K = 512 + 1024)
//   h2' = tanh( h1' @ W2 + h2 @ U2 + b2 )                (K = 1024 + 1024)
// Final: out = sigmoid(h2 @ Wo + bo)
//
// M = 2048 (batch), N = 1024 (units). 64x64 output tiles, 256 thr, 4x4/thread.

#define M_TOTAL 2048
#define N_TOTAL 1024
#define TSEQ    80
#define KT      16

__device__ __forceinline__ void gemm_phase(
    float acc[4][4],
    const float* __restrict__ Abase,   // [rows x K] row-major (or emb table)
    const int*   __restrict__ tok,     // gather indices (tokens), or nullptr
    int t, int K,
    const float* __restrict__ B,       // [K x 1024] row-major
    int bm0, int bn0, int tx, int ty, int tid,
    float (*As)[68], float (*Bs)[64])
{
    const int ar  = tid >> 2;          // 0..63  A-tile row
    const int akq = (tid & 3) << 2;    // 0,4,8,12  A-tile k quad
    const int bkr = tid >> 4;          // 0..15  B-tile k row
    const int bnq = (tid & 15) << 2;   // 0..60  B-tile n quad

    const float* arow;
    if (tok) {
        const int token = tok[(size_t)(bm0 + ar) * TSEQ + t];
        arow = Abase + (size_t)token * K;
    } else {
        arow = Abase + (size_t)(bm0 + ar) * K;
    }

    for (int k0 = 0; k0 < K; k0 += KT) {
        const float4 av = *(const float4*)(arow + k0 + akq);
        const float4 bv = *(const float4*)(B + (size_t)(k0 + bkr) * N_TOTAL + bn0 + bnq);
        __syncthreads();               // protect previous tile's reads
        As[akq + 0][ar] = av.x;
        As[akq + 1][ar] = av.y;
        As[akq + 2][ar] = av.z;
        As[akq + 3][ar] = av.w;
        *(float4*)(&Bs[bkr][bnq]) = bv;
        __syncthreads();
        #pragma unroll
        for (int k = 0; k < KT; ++k) {
            const float4 a4 = *(const float4*)(&As[k][ty << 2]);
            const float4 b4 = *(const float4*)(&Bs[k][tx << 2]);
            const float ae[4] = {a4.x, a4.y, a4.z, a4.w};
            const float be[4] = {b4.x, b4.y, b4.z, b4.w};
            #pragma unroll
            for (int i = 0; i < 4; ++i)
                #pragma unroll
                for (int j = 0; j < 4; ++j)
                    acc[i][j] = fmaf(ae[i], be[j], acc[i][j]);
        }
    }
}

__global__ __launch_bounds__(256) void rnn_step(
    float* __restrict__ C,             // [2048 x 1024] h_out
    const float* __restrict__ A1,      // gather table (emb) or [2048 x K1]
    const int*   __restrict__ tok,     // tokens or nullptr
    int t, int K1,
    const float* __restrict__ W,       // [K1 x 1024]
    const float* __restrict__ A2,      // [2048 x 1024] h_in
    const float* __restrict__ U,       // [1024 x 1024]
    const float* __restrict__ bias)    // [1024]
{
    __shared__ __align__(16) float As[KT][68];
    __shared__ __align__(16) float Bs[KT][64];
    const int tid = threadIdx.x;
    const int tx = tid & 15;           // output col / 4
    const int ty = tid >> 4;           // output row / 4
    const int bn0 = blockIdx.x * 64;
    const int bm0 = blockIdx.y * 64;

    float acc[4][4] = {};
    gemm_phase(acc, A1, tok, t, K1,   W, bm0, bn0, tx, ty, tid, As, Bs);
    gemm_phase(acc, A2, nullptr, 0, 1024, U, bm0, bn0, tx, ty, tid, As, Bs);

    const int nb = bn0 + (tx << 2);
    const float bsx = bias[nb + 0], bsy = bias[nb + 1],
                bsz = bias[nb + 2], bsw = bias[nb + 3];
    #pragma unroll
    for (int i = 0; i < 4; ++i) {
        const int row = bm0 + (ty << 2) + i;
        float4 o;
        o.x = tanhf(acc[i][0] + bsx);
        o.y = tanhf(acc[i][1] + bsy);
        o.z = tanhf(acc[i][2] + bsz);
        o.w = tanhf(acc[i][3] + bsw);
        *(float4*)(C + (size_t)row * N_TOTAL + nb) = o;
    }
}

// out[b] = sigmoid(dot(h2[b,:], Wo) + bo), one wave per row
__global__ __launch_bounds__(256) void out_kernel(
    float* __restrict__ out,
    const float* __restrict__ h2,
    const float* __restrict__ Wo,
    const float* __restrict__ bo)
{
    const int row  = blockIdx.x * 4 + (threadIdx.x >> 6);
    const int lane = threadIdx.x & 63;
    float s = 0.f;
    const float* hr = h2 + (size_t)row * N_TOTAL;
    for (int k = lane; k < N_TOTAL; k += 64)
        s += hr[k] * Wo[k];
    #pragma unroll
    for (int off = 32; off; off >>= 1)
        s += __shfl_down(s, off);
    if (lane == 0)
        out[row] = 1.f / (1.f + expf(-(s + bo[0])));
}

extern "C" void kernel_launch(void* const* d_in, const int* in_sizes, int n_in,
                              void* d_out, int out_size, void* d_ws, size_t ws_size,
                              hipStream_t stream) {
    const int*   tokens = (const int*)  d_in[0];
    const float* emb    = (const float*)d_in[1];
    const float* W1     = (const float*)d_in[2];
    const float* U1     = (const float*)d_in[3];
    const float* b1     = (const float*)d_in[4];
    const float* W2     = (const float*)d_in[5];
    const float* U2     = (const float*)d_in[6];
    const float* b2     = (const float*)d_in[7];
    const float* Wo     = (const float*)d_in[8];
    const float* bo     = (const float*)d_in[9];
    float* out = (float*)d_out;

    char* ws = (char*)d_ws;
    const size_t HB = (size_t)M_TOTAL * N_TOTAL * sizeof(float);  // 8 MB
    float* h1a = (float*)(ws + 0 * HB);
    float* h1b = (float*)(ws + 1 * HB);
    float* h2a = (float*)(ws + 2 * HB);
    float* h2b = (float*)(ws + 3 * HB);

    // h0 = 0 for both layers (must re-init every call; ws is not re-poisoned)
    hipMemsetAsync(h1a, 0, HB, stream);
    hipMemsetAsync(h2a, 0, HB, stream);

    dim3 grid(N_TOTAL / 64, M_TOTAL / 64);  // 16 x 32 = 512 blocks
    dim3 block(256);

    float* h1c = h1a; float* h1n = h1b;
    float* h2c = h2a; float* h2n = h2b;
    for (int t = 0; t < TSEQ; ++t) {
        rnn_step<<<grid, block, 0, stream>>>(h1n, emb, tokens, t, 512,  W1, h1c, U1, b1);
        rnn_step<<<grid, block, 0, stream>>>(h2n, h1n, nullptr, 0, 1024, W2, h2c, U2, b2);
        float* tmp;
        tmp = h1c; h1c = h1n; h1n = tmp;
        tmp = h2c; h2c = h2n; h2n = tmp;
    }

    out_kernel<<<dim3(M_TOTAL / 4), dim3(256), 0, stream>>>(out, h2c, Wo, bo);
}

// Round 2
// 4276.878 us; speedup vs baseline: 4.2609x; 4.2609x over previous
//
#include <hip/hip_runtime.h>
#include <math.h>

#define M_TOTAL 2048
#define N_TOTAL 1024
#define TSEQ    80
#define EMB_D   512
#define BM 64
#define BN 64
#define BK 64

typedef __attribute__((ext_vector_type(8))) short bf16x8;
typedef __attribute__((ext_vector_type(4))) float f32x4;

__device__ __forceinline__ ushort f2bf(float f) {
    union { float f; unsigned u; } v; v.f = f;
    unsigned r = v.u + 0x7FFFu + ((v.u >> 16) & 1u);
    return (ushort)(r >> 16);
}
__device__ __forceinline__ float bf2f(ushort h) {
    union { unsigned u; float f; } v; v.u = ((unsigned)h) << 16;
    return v.f;
}

__device__ __forceinline__ void gload_lds16(const ushort* g, ushort* l) {
    __builtin_amdgcn_global_load_lds(
        (const __attribute__((address_space(1))) void*)g,
        (__attribute__((address_space(3))) void*)l, 16, 0, 0);
}

#define VM0() asm volatile("s_waitcnt vmcnt(0)" ::: "memory")

// Stage one 64x64 bf16 A-tile and one 64x64 bf16 B-tile (both [row][k], k
// contiguous) via global_load_lds, with XOR-swizzled SOURCE so that the
// swizzled ds_read on the consume side is conflict-free (both-sides rule).
__device__ __forceinline__ void stage_pair(
    ushort* __restrict__ Asb, ushort* __restrict__ Bsb,
    const ushort* __restrict__ A, int bm0, int Ka,
    const ushort* __restrict__ Bt, int bn0, int Kb,
    int k0, int w, int l)
{
    const int lr = l >> 3;                    // 0..7 sub-row within 8-row slab
    const int se = ((l & 7) ^ lr) << 3;       // pre-swizzled source k-element
    #pragma unroll
    for (int j = 0; j < 2; ++j) {
        const int rbase = w * 16 + j * 8;     // wave-uniform row base
        gload_lds16(A  + (size_t)(bm0 + rbase + lr) * Ka + k0 + se,
                    Asb + rbase * BK + l * 8);
        gload_lds16(Bt + (size_t)(bn0 + rbase + lr) * Kb + k0 + se,
                    Bsb + rbase * BK + l * 8);
    }
}

__device__ __forceinline__ void compute_chunk(
    const ushort* __restrict__ Asb, const ushort* __restrict__ Bsb,
    int wr, int wc, int l, f32x4 (&acc)[2][2])
{
    #pragma unroll
    for (int kf = 0; kf < 2; ++kf) {
        const int ke = kf * 32 + (l >> 4) * 8;
        bf16x8 a[2], b[2];
        #pragma unroll
        for (int mf = 0; mf < 2; ++mf) {
            const int row = wr * 32 + mf * 16 + (l & 15);
            a[mf] = *(const bf16x8*)&Asb[row * BK + (ke ^ ((row & 7) << 3))];
        }
        #pragma unroll
        for (int nf = 0; nf < 2; ++nf) {
            const int nn = wc * 32 + nf * 16 + (l & 15);
            b[nf] = *(const bf16x8*)&Bsb[nn * BK + (ke ^ ((nn & 7) << 3))];
        }
        #pragma unroll
        for (int mf = 0; mf < 2; ++mf)
            #pragma unroll
            for (int nf = 0; nf < 2; ++nf)
                acc[mf][nf] = __builtin_amdgcn_mfma_f32_16x16x32_bf16(
                    a[mf], b[nf], acc[mf][nf], 0, 0, 0);
    }
}

// One RNN layer step: C = tanh( [x-phase] + A_a@Ba + A_b@Bb + bias ), bf16 out.
__global__ __launch_bounds__(256) void rnn_step(
    ushort* __restrict__ C,                 // [2048][1024] bf16
    const float* __restrict__ emb,          // emb table or null
    const int* __restrict__ tok, int t,
    const ushort* __restrict__ WxT,         // [1024][512] bf16, x-phase B
    const ushort* __restrict__ Aa,          // bf16 [2048][1024] or null
    const ushort* __restrict__ BaT,         // [1024][1024] bf16
    const ushort* __restrict__ Ab,          // bf16 [2048][1024] or null
    const ushort* __restrict__ BbT,         // [1024][1024] bf16
    const float* __restrict__ bias)
{
    __shared__ ushort As[2][BM * BK];
    __shared__ ushort Bs[2][BN * BK];
    const int tid = threadIdx.x;
    const int w = tid >> 6, l = tid & 63;
    const int wr = w >> 1, wc = w & 1;
    const int bn0 = blockIdx.x * BN;
    const int bm0 = blockIdx.y * BM;

    f32x4 acc[2][2] = {};
    int cur = 0;

    // ---- x phase: A = bf16(emb[tokens[:,t]]) (fp32 gather+convert), K=512
    if (emb) {
        const int xrow = tid >> 2;                 // 0..63
        const int kq   = (tid & 3) << 4;           // 0,16,32,48 (floats)
        const int swz  = (xrow & 7) << 3;
        const int token = tok[(size_t)(bm0 + xrow) * TSEQ + t];
        const float* xr = emb + (size_t)token * EMB_D;
        for (int ck = 0; ck < EMB_D / BK; ++ck) {
            const int k0 = ck << 6;
            const float4 v0 = *(const float4*)(xr + k0 + kq + 0);
            const float4 v1 = *(const float4*)(xr + k0 + kq + 4);
            const float4 v2 = *(const float4*)(xr + k0 + kq + 8);
            const float4 v3 = *(const float4*)(xr + k0 + kq + 12);
            __syncthreads();   // prior chunk's reads retired
            {   // B: WxT via global_load_lds
                const int lr = l >> 3;
                const int se = ((l & 7) ^ lr) << 3;
                #pragma unroll
                for (int j = 0; j < 2; ++j) {
                    const int rbase = w * 16 + j * 8;
                    gload_lds16(WxT + (size_t)(bn0 + rbase + lr) * EMB_D + k0 + se,
                                Bs[cur] + rbase * BK + l * 8);
                }
            }
            const unsigned w0 = f2bf(v0.x) | (f2bf(v0.y) << 16);
            const unsigned w1 = f2bf(v0.z) | (f2bf(v0.w) << 16);
            const unsigned w2 = f2bf(v1.x) | (f2bf(v1.y) << 16);
            const unsigned w3 = f2bf(v1.z) | (f2bf(v1.w) << 16);
            const unsigned w4 = f2bf(v2.x) | (f2bf(v2.y) << 16);
            const unsigned w5 = f2bf(v2.z) | (f2bf(v2.w) << 16);
            const unsigned w6 = f2bf(v3.x) | (f2bf(v3.y) << 16);
            const unsigned w7 = f2bf(v3.z) | (f2bf(v3.w) << 16);
            *(uint4*)&As[cur][xrow * BK + ((kq + 0) ^ swz)] = make_uint4(w0, w1, w2, w3);
            *(uint4*)&As[cur][xrow * BK + ((kq + 8) ^ swz)] = make_uint4(w4, w5, w6, w7);
            VM0();
            __syncthreads();
            compute_chunk(As[cur], Bs[cur], wr, wc, l, acc);
        }
        __syncthreads();       // retire last chunk before next phase stages
    }

    // ---- bf16 phases (double-buffered global_load_lds, T3-minimum schedule)
    const ushort* Alist[2] = { Aa, Ab };
    const ushort* Blist[2] = { BaT, BbT };
    #pragma unroll
    for (int p = 0; p < 2; ++p) {
        const ushort* A  = Alist[p];
        const ushort* Bt = Blist[p];
        if (!A) continue;
        stage_pair(As[cur], Bs[cur], A, bm0, N_TOTAL, Bt, bn0, N_TOTAL, 0, w, l);
        VM0();
        __syncthreads();
        for (int ck = 0; ck < N_TOTAL / BK; ++ck) {
            if (ck + 1 < N_TOTAL / BK)
                stage_pair(As[cur ^ 1], Bs[cur ^ 1], A, bm0, N_TOTAL,
                           Bt, bn0, N_TOTAL, (ck + 1) << 6, w, l);
            compute_chunk(As[cur], Bs[cur], wr, wc, l, acc);
            VM0();
            __syncthreads();
            cur ^= 1;
        }
    }

    // ---- epilogue: bias + tanh, write bf16
    #pragma unroll
    for (int nf = 0; nf < 2; ++nf) {
        const int col = bn0 + wc * 32 + nf * 16 + (l & 15);
        const float bz = bias[col];
        #pragma unroll
        for (int mf = 0; mf < 2; ++mf) {
            const int rbase = bm0 + wr * 32 + mf * 16 + (l >> 4) * 4;
            #pragma unroll
            for (int r = 0; r < 4; ++r) {
                const float vv = tanhf(acc[mf][nf][r] + bz);
                C[(size_t)(rbase + r) * N_TOTAL + col] = f2bf(vv);
            }
        }
    }
}

// W [K][N] fp32  ->  WT [N][K] bf16 (once per call)
__global__ __launch_bounds__(256) void transpose_convert(
    ushort* __restrict__ outT, const float* __restrict__ in, int K, int N)
{
    __shared__ float tile[64][65];
    const int tiles_n = N >> 6;
    const int k0 = (blockIdx.x / tiles_n) << 6;
    const int n0 = (blockIdx.x % tiles_n) << 6;
    const int tid = threadIdx.x;
    const int r = tid >> 4, c = (tid & 15) << 2;
    #pragma unroll
    for (int i = 0; i < 4; ++i) {
        const float4 v = *(const float4*)(in + (size_t)(k0 + r + i * 16) * N + n0 + c);
        tile[r + i * 16][c + 0] = v.x;
        tile[r + i * 16][c + 1] = v.y;
        tile[r + i * 16][c + 2] = v.z;
        tile[r + i * 16][c + 3] = v.w;
    }
    __syncthreads();
    const int n = tid >> 2, ks = (tid & 3) << 4;
    unsigned pk[8];
    #pragma unroll
    for (int j = 0; j < 8; ++j) {
        const unsigned lo = f2bf(tile[ks + 2 * j][n]);
        const unsigned hi = f2bf(tile[ks + 2 * j + 1][n]);
        pk[j] = lo | (hi << 16);
    }
    ushort* dst = outT + (size_t)(n0 + n) * K + k0 + ks;
    *(uint4*)(dst + 0) = make_uint4(pk[0], pk[1], pk[2], pk[3]);
    *(uint4*)(dst + 8) = make_uint4(pk[4], pk[5], pk[6], pk[7]);
}

// out[b] = sigmoid(dot(h2[b,:], Wo) + bo)
__global__ __launch_bounds__(256) void out_kernel(
    float* __restrict__ out, const ushort* __restrict__ h2,
    const float* __restrict__ Wo, const float* __restrict__ bo)
{
    const int row  = blockIdx.x * 4 + (threadIdx.x >> 6);
    const int lane = threadIdx.x & 63;
    const ushort* hr = h2 + (size_t)row * N_TOTAL;
    float s = 0.f;
    for (int k = lane; k < N_TOTAL; k += 64)
        s += bf2f(hr[k]) * Wo[k];
    #pragma unroll
    for (int off = 32; off; off >>= 1)
        s += __shfl_down(s, off);
    if (lane == 0)
        out[row] = 1.f / (1.f + expf(-(s + bo[0])));
}

extern "C" void kernel_launch(void* const* d_in, const int* in_sizes, int n_in,
                              void* d_out, int out_size, void* d_ws, size_t ws_size,
                              hipStream_t stream) {
    const int*   tokens = (const int*)  d_in[0];
    const float* emb    = (const float*)d_in[1];
    const float* W1     = (const float*)d_in[2];
    const float* U1     = (const float*)d_in[3];
    const float* b1     = (const float*)d_in[4];
    const float* W2     = (const float*)d_in[5];
    const float* U2     = (const float*)d_in[6];
    const float* b2     = (const float*)d_in[7];
    const float* Wo     = (const float*)d_in[8];
    const float* bo     = (const float*)d_in[9];
    float* out = (float*)d_out;

    char* ws = (char*)d_ws;
    const size_t HB = (size_t)M_TOTAL * N_TOTAL * sizeof(ushort);  // 4 MB
    ushort* h1a = (ushort*)(ws + 0 * HB);
    ushort* h1b = (ushort*)(ws + 1 * HB);
    ushort* h2a = (ushort*)(ws + 2 * HB);
    ushort* h2b = (ushort*)(ws + 3 * HB);
    size_t off = 4 * HB;
    ushort* W1T = (ushort*)(ws + off); off += (size_t)N_TOTAL * EMB_D   * 2;
    ushort* U1T = (ushort*)(ws + off); off += (size_t)N_TOTAL * N_TOTAL * 2;
    ushort* W2T = (ushort*)(ws + off); off += (size_t)N_TOTAL * N_TOTAL * 2;
    ushort* U2T = (ushort*)(ws + off);

    hipMemsetAsync(h1a, 0, HB, stream);
    hipMemsetAsync(h2a, 0, HB, stream);

    transpose_convert<<<dim3((EMB_D  / 64) * (N_TOTAL / 64)), 256, 0, stream>>>(W1T, W1, EMB_D,   N_TOTAL);
    transpose_convert<<<dim3((N_TOTAL / 64) * (N_TOTAL / 64)), 256, 0, stream>>>(U1T, U1, N_TOTAL, N_TOTAL);
    transpose_convert<<<dim3((N_TOTAL / 64) * (N_TOTAL / 64)), 256, 0, stream>>>(W2T, W2, N_TOTAL, N_TOTAL);
    transpose_convert<<<dim3((N_TOTAL / 64) * (N_TOTAL / 64)), 256, 0, stream>>>(U2T, U2, N_TOTAL, N_TOTAL);

    dim3 grid(N_TOTAL / BN, M_TOTAL / BM);   // 16 x 32 = 512 blocks
    dim3 block(256);

    ushort* h1c = h1a; ushort* h1n = h1b;
    ushort* h2c = h2a; ushort* h2n = h2b;
    for (int t = 0; t < TSEQ; ++t) {
        rnn_step<<<grid, block, 0, stream>>>(h1n, emb, tokens, t, W1T,
                                             h1c, U1T, nullptr, nullptr, b1);
        rnn_step<<<grid, block, 0, stream>>>(h2n, nullptr, nullptr, 0, nullptr,
                                             h1n, W2T, h2c, U2T, b2);
        ushort* tmp;
        tmp = h1c; h1c = h1n; h1n = tmp;
        tmp = h2c; h2c = h2n; h2n = tmp;
    }

    out_kernel<<<dim3(M_TOTAL / 4), dim3(256), 0, stream>>>(out, h2c, Wo, bo);
}

// Round 3
// 3046.435 us; speedup vs baseline: 5.9819x; 1.4039x over previous
//
#include <hip/hip_runtime.h>
#include <math.h>

#define M_TOTAL 2048
#define N_TOTAL 1024
#define TSEQ    80
#define EMB_D   512
#define BM 64
#define BN 64
#define BK 64

typedef __attribute__((ext_vector_type(8))) short bf16x8;
typedef __attribute__((ext_vector_type(4))) float f32x4;

__device__ __forceinline__ ushort f2bf(float f) {
    union { float f; unsigned u; } v; v.f = f;
    unsigned r = v.u + 0x7FFFu + ((v.u >> 16) & 1u);
    return (ushort)(r >> 16);
}
__device__ __forceinline__ float bf2f(ushort h) {
    union { unsigned u; float f; } v; v.u = ((unsigned)h) << 16;
    return v.f;
}

__device__ __forceinline__ void gload_lds16(const ushort* g, ushort* l) {
    __builtin_amdgcn_global_load_lds(
        (const __attribute__((address_space(1))) void*)g,
        (__attribute__((address_space(3))) void*)l, 16, 0, 0);
}

#define VM0() asm volatile("s_waitcnt vmcnt(0)" ::: "memory")

// Stage 64x64 bf16 A- and B-tiles ([row][k], k contiguous) via global_load_lds
// with XOR-pre-swizzled SOURCE (both-sides rule; read side applies same XOR).
__device__ __forceinline__ void stage_pair(
    ushort* __restrict__ Asb, ushort* __restrict__ Bsb,
    const ushort* __restrict__ A, int bm0, int Ka,
    const ushort* __restrict__ Bt, int bn0, int Kb,
    int k0, int w, int l)
{
    const int lr = l >> 3;
    const int se = ((l & 7) ^ lr) << 3;
    #pragma unroll
    for (int j = 0; j < 2; ++j) {
        const int rbase = w * 16 + j * 8;
        gload_lds16(A  + (size_t)(bm0 + rbase + lr) * Ka + k0 + se,
                    Asb + rbase * BK + l * 8);
        gload_lds16(Bt + (size_t)(bn0 + rbase + lr) * Kb + k0 + se,
                    Bsb + rbase * BK + l * 8);
    }
}

__device__ __forceinline__ void compute_chunk(
    const ushort* __restrict__ Asb, const ushort* __restrict__ Bsb,
    int wr, int wc, int l, f32x4 (&acc)[2][2])
{
    #pragma unroll
    for (int kf = 0; kf < 2; ++kf) {
        const int ke = kf * 32 + (l >> 4) * 8;
        bf16x8 a[2], b[2];
        #pragma unroll
        for (int mf = 0; mf < 2; ++mf) {
            const int row = wr * 32 + mf * 16 + (l & 15);
            a[mf] = *(const bf16x8*)&Asb[row * BK + (ke ^ ((row & 7) << 3))];
        }
        #pragma unroll
        for (int nf = 0; nf < 2; ++nf) {
            const int nn = wc * 32 + nf * 16 + (l & 15);
            b[nf] = *(const bf16x8*)&Bsb[nn * BK + (ke ^ ((nn & 7) << 3))];
        }
        #pragma unroll
        for (int mf = 0; mf < 2; ++mf)
            #pragma unroll
            for (int nf = 0; nf < 2; ++nf)
                acc[mf][nf] = __builtin_amdgcn_mfma_f32_16x16x32_bf16(
                    a[mf], b[nf], acc[mf][nf], 0, 0, 0);
    }
}

// Full double-buffered K=1024 phase: acc += A[bm0:+64]@Bt[bn0:+64]^T
__device__ __forceinline__ void run_phase(
    f32x4 (&acc)[2][2], ushort (*As)[BM * BK], ushort (*Bs)[BN * BK],
    const ushort* __restrict__ A, int bm0,
    const ushort* __restrict__ Bt, int bn0,
    int wr, int wc, int w, int l)
{
    int cur = 0;
    stage_pair(As[0], Bs[0], A, bm0, N_TOTAL, Bt, bn0, N_TOTAL, 0, w, l);
    VM0();
    __syncthreads();
    for (int ck = 0; ck < N_TOTAL / BK; ++ck) {
        if (ck + 1 < N_TOTAL / BK)
            stage_pair(As[cur ^ 1], Bs[cur ^ 1], A, bm0, N_TOTAL,
                       Bt, bn0, N_TOTAL, (ck + 1) << 6, w, l);
        compute_chunk(As[cur], Bs[cur], wr, wc, l, acc);
        VM0();
        __syncthreads();
        cur ^= 1;
    }
}

// Fused per-step kernel. blockIdx.z==0: layer1 (h1n = tanh(xw1_t + h1c@U1 + b1))
//                        blockIdx.z==1: layer2 (h2n = tanh(h1c@W2 + h2c@U2 + b2))
__global__ __launch_bounds__(256) void fused_step(
    ushort* __restrict__ h1n, const ushort* __restrict__ h1c,
    const ushort* __restrict__ U1T, const ushort* __restrict__ xw_t,
    const float* __restrict__ b1,
    ushort* __restrict__ h2n, const ushort* __restrict__ h2c,
    const ushort* __restrict__ W2T, const ushort* __restrict__ U2T,
    const float* __restrict__ b2,
    int do_l1, int do_l2)
{
    __shared__ ushort As[2][BM * BK];
    __shared__ ushort Bs[2][BN * BK];
    const int tid = threadIdx.x;
    const int w = tid >> 6, l = tid & 63;
    const int wr = w >> 1, wc = w & 1;
    const int bn0 = blockIdx.x * BN;
    const int bm0 = blockIdx.y * BM;
    const int layer = blockIdx.z;

    if (layer == 0 && !do_l1) return;
    if (layer == 1 && !do_l2) return;

    f32x4 acc[2][2] = {};

    if (layer == 0) {
        run_phase(acc, As, Bs, h1c, bm0, U1T, bn0, wr, wc, w, l);
    } else {
        run_phase(acc, As, Bs, h1c, bm0, W2T, bn0, wr, wc, w, l);
        run_phase(acc, As, Bs, h2c, bm0, U2T, bn0, wr, wc, w, l);
    }

    ushort* C = (layer == 0) ? h1n : h2n;
    const float* bias = (layer == 0) ? b1 : b2;
    #pragma unroll
    for (int nf = 0; nf < 2; ++nf) {
        const int col = bn0 + wc * 32 + nf * 16 + (l & 15);
        const float bz = bias[col];
        #pragma unroll
        for (int mf = 0; mf < 2; ++mf) {
            const int rbase = bm0 + wr * 32 + mf * 16 + (l >> 4) * 4;
            #pragma unroll
            for (int r = 0; r < 4; ++r) {
                float vv = acc[mf][nf][r] + bz;
                if (layer == 0)
                    vv += bf2f(xw_t[(size_t)(rbase + r) * N_TOTAL + col]);
                C[(size_t)(rbase + r) * N_TOTAL + col] = f2bf(tanhf(vv));
            }
        }
    }
}

// XW1[t*2048+b][n] = emb[tokens[b][t]] @ W1  (bf16 out, no bias). M=163840.
__global__ __launch_bounds__(256) void xw1_gemm(
    ushort* __restrict__ out,              // [163840][1024] bf16
    const float* __restrict__ emb,         // [50000][512] fp32
    const int* __restrict__ tok,           // [2048][80]
    const ushort* __restrict__ W1T)        // [1024][512] bf16
{
    __shared__ ushort As[BM * BK];
    __shared__ ushort Bs[BN * BK];
    const int tid = threadIdx.x;
    const int w = tid >> 6, l = tid & 63;
    const int wr = w >> 1, wc = w & 1;
    const int bn0 = blockIdx.x * BN;
    const int bm0 = blockIdx.y * BM;

    f32x4 acc[2][2] = {};

    const int xrow = tid >> 2;               // 0..63
    const int kq   = (tid & 3) << 4;         // 0,16,32,48 floats
    const int swz  = (xrow & 7) << 3;
    const int grow = bm0 + xrow;             // global M row
    const int token = tok[(grow & (M_TOTAL - 1)) * TSEQ + (grow >> 11)];
    const float* xr = emb + (size_t)token * EMB_D;

    for (int ck = 0; ck < EMB_D / BK; ++ck) {
        const int k0 = ck << 6;
        const float4 v0 = *(const float4*)(xr + k0 + kq + 0);
        const float4 v1 = *(const float4*)(xr + k0 + kq + 4);
        const float4 v2 = *(const float4*)(xr + k0 + kq + 8);
        const float4 v3 = *(const float4*)(xr + k0 + kq + 12);
        __syncthreads();
        {   // stage B tile (W1T) via global_load_lds, pre-swizzled source
            const int lr = l >> 3;
            const int se = ((l & 7) ^ lr) << 3;
            #pragma unroll
            for (int j = 0; j < 2; ++j) {
                const int rbase = w * 16 + j * 8;
                gload_lds16(W1T + (size_t)(bn0 + rbase + lr) * EMB_D + k0 + se,
                            Bs + rbase * BK + l * 8);
            }
        }
        const unsigned w0 = f2bf(v0.x) | (f2bf(v0.y) << 16);
        const unsigned w1 = f2bf(v0.z) | (f2bf(v0.w) << 16);
        const unsigned w2 = f2bf(v1.x) | (f2bf(v1.y) << 16);
        const unsigned w3 = f2bf(v1.z) | (f2bf(v1.w) << 16);
        const unsigned w4 = f2bf(v2.x) | (f2bf(v2.y) << 16);
        const unsigned w5 = f2bf(v2.z) | (f2bf(v2.w) << 16);
        const unsigned w6 = f2bf(v3.x) | (f2bf(v3.y) << 16);
        const unsigned w7 = f2bf(v3.z) | (f2bf(v3.w) << 16);
        *(uint4*)&As[xrow * BK + ((kq + 0) ^ swz)] = make_uint4(w0, w1, w2, w3);
        *(uint4*)&As[xrow * BK + ((kq + 8) ^ swz)] = make_uint4(w4, w5, w6, w7);
        VM0();
        __syncthreads();
        compute_chunk(As, Bs, wr, wc, l, acc);
    }

    #pragma unroll
    for (int nf = 0; nf < 2; ++nf) {
        const int col = bn0 + wc * 32 + nf * 16 + (l & 15);
        #pragma unroll
        for (int mf = 0; mf < 2; ++mf) {
            const int rbase = bm0 + wr * 32 + mf * 16 + (l >> 4) * 4;
            #pragma unroll
            for (int r = 0; r < 4; ++r)
                out[(size_t)(rbase + r) * N_TOTAL + col] = f2bf(acc[mf][nf][r]);
        }
    }
}

// W [K][N] fp32 -> WT [N][K] bf16
__global__ __launch_bounds__(256) void transpose_convert(
    ushort* __restrict__ outT, const float* __restrict__ in, int K, int N)
{
    __shared__ float tile[64][65];
    const int tiles_n = N >> 6;
    const int k0 = (blockIdx.x / tiles_n) << 6;
    const int n0 = (blockIdx.x % tiles_n) << 6;
    const int tid = threadIdx.x;
    const int r = tid >> 4, c = (tid & 15) << 2;
    #pragma unroll
    for (int i = 0; i < 4; ++i) {
        const float4 v = *(const float4*)(in + (size_t)(k0 + r + i * 16) * N + n0 + c);
        tile[r + i * 16][c + 0] = v.x;
        tile[r + i * 16][c + 1] = v.y;
        tile[r + i * 16][c + 2] = v.z;
        tile[r + i * 16][c + 3] = v.w;
    }
    __syncthreads();
    const int n = tid >> 2, ks = (tid & 3) << 4;
    unsigned pk[8];
    #pragma unroll
    for (int j = 0; j < 8; ++j) {
        const unsigned lo = f2bf(tile[ks + 2 * j][n]);
        const unsigned hi = f2bf(tile[ks + 2 * j + 1][n]);
        pk[j] = lo | (hi << 16);
    }
    ushort* dst = outT + (size_t)(n0 + n) * K + k0 + ks;
    *(uint4*)(dst + 0) = make_uint4(pk[0], pk[1], pk[2], pk[3]);
    *(uint4*)(dst + 8) = make_uint4(pk[4], pk[5], pk[6], pk[7]);
}

__global__ __launch_bounds__(256) void out_kernel(
    float* __restrict__ out, const ushort* __restrict__ h2,
    const float* __restrict__ Wo, const float* __restrict__ bo)
{
    const int row  = blockIdx.x * 4 + (threadIdx.x >> 6);
    const int lane = threadIdx.x & 63;
    const ushort* hr = h2 + (size_t)row * N_TOTAL;
    float s = 0.f;
    for (int k = lane; k < N_TOTAL; k += 64)
        s += bf2f(hr[k]) * Wo[k];
    #pragma unroll
    for (int off = 32; off; off >>= 1)
        s += __shfl_down(s, off);
    if (lane == 0)
        out[row] = 1.f / (1.f + expf(-(s + bo[0])));
}

extern "C" void kernel_launch(void* const* d_in, const int* in_sizes, int n_in,
                              void* d_out, int out_size, void* d_ws, size_t ws_size,
                              hipStream_t stream) {
    const int*   tokens = (const int*)  d_in[0];
    const float* emb    = (const float*)d_in[1];
    const float* W1     = (const float*)d_in[2];
    const float* U1     = (const float*)d_in[3];
    const float* b1     = (const float*)d_in[4];
    const float* W2     = (const float*)d_in[5];
    const float* U2     = (const float*)d_in[6];
    const float* b2     = (const float*)d_in[7];
    const float* Wo     = (const float*)d_in[8];
    const float* bo     = (const float*)d_in[9];
    float* out = (float*)d_out;

    char* ws = (char*)d_ws;
    const size_t HB = (size_t)M_TOTAL * N_TOTAL * sizeof(ushort);  // 4 MB
    ushort* h1a = (ushort*)(ws + 0 * HB);
    ushort* h1b = (ushort*)(ws + 1 * HB);
    ushort* h2a = (ushort*)(ws + 2 * HB);
    ushort* h2b = (ushort*)(ws + 3 * HB);
    size_t off = 4 * HB;
    ushort* W1T = (ushort*)(ws + off); off += (size_t)N_TOTAL * EMB_D   * 2;
    ushort* U1T = (ushort*)(ws + off); off += (size_t)N_TOTAL * N_TOTAL * 2;
    ushort* W2T = (ushort*)(ws + off); off += (size_t)N_TOTAL * N_TOTAL * 2;
    ushort* U2T = (ushort*)(ws + off); off += (size_t)N_TOTAL * N_TOTAL * 2;
    ushort* XW1 = (ushort*)(ws + off);   // [80*2048][1024] bf16 = 335.5 MB

    hipMemsetAsync(h1a, 0, HB, stream);
    hipMemsetAsync(h2a, 0, HB, stream);

    transpose_convert<<<dim3((EMB_D  / 64) * (N_TOTAL / 64)), 256, 0, stream>>>(W1T, W1, EMB_D,   N_TOTAL);
    transpose_convert<<<dim3((N_TOTAL / 64) * (N_TOTAL / 64)), 256, 0, stream>>>(U1T, U1, N_TOTAL, N_TOTAL);
    transpose_convert<<<dim3((N_TOTAL / 64) * (N_TOTAL / 64)), 256, 0, stream>>>(W2T, W2, N_TOTAL, N_TOTAL);
    transpose_convert<<<dim3((N_TOTAL / 64) * (N_TOTAL / 64)), 256, 0, stream>>>(U2T, U2, N_TOTAL, N_TOTAL);

    // Hoisted input projection for layer 1 (fully parallel, off critical path)
    xw1_gemm<<<dim3(N_TOTAL / BN, (TSEQ * M_TOTAL) / BM), 256, 0, stream>>>(
        XW1, emb, tokens, W1T);

    dim3 grid(N_TOTAL / BN, M_TOTAL / BM, 2);   // 16 x 32 x 2 = 1024 blocks
    dim3 block(256);

    ushort* h1c = h1a; ushort* h1n = h1b;
    ushort* h2c = h2a; ushort* h2n = h2b;
    ushort* tmp;
    for (int i = 0; i <= TSEQ; ++i) {
        const int do_l1 = (i < TSEQ);
        const int do_l2 = (i >= 1);
        fused_step<<<grid, block, 0, stream>>>(
            h1n, h1c, U1T, XW1 + (size_t)i * M_TOTAL * N_TOTAL, b1,
            h2n, h2c, W2T, U2T, b2, do_l1, do_l2);
        if (do_l1) { tmp = h1c; h1c = h1n; h1n = tmp; }
        if (do_l2) { tmp = h2c; h2c = h2n; h2n = tmp; }
    }

    out_kernel<<<dim3(M_TOTAL / 4), dim3(256), 0, stream>>>(out, h2c, Wo, bo);
}